// Round 1
// baseline (119.101 us; speedup 1.0000x reference)
//
#include <hip/hip_runtime.h>
#include <hip/hip_bf16.h>

// InfoNCE loss, N=4096, D=256, tau=0.5.
// loss = mean over 2n rows of [ logsumexp_{k != i} (2 * Z_i . Z_k) - 2 * (xn_i . yn_i) ]
// where Z = concat(xn, yn), rows L2-normalized.
// Since scores are bounded in [-2,2], sum-of-exp needs no running max.

#define NROWS 8192
#define DDIM  256
#define BM    128        // rows per block
#define BN    64         // cols per LDS tile
#define COLSPLIT 8       // column split -> grid = 64 * 8 = 512 blocks
#define COLS_PER (NROWS / COLSPLIT)   // 1024

typedef __attribute__((ext_vector_type(8))) __bf16 bf16x8_t;
typedef __attribute__((ext_vector_type(4))) float  f32x4_t;

typedef __attribute__((address_space(1))) const void* as1_cvp;
typedef __attribute__((address_space(3))) void*       as3_vp;

// ---------------- K1: normalize rows of x,y -> bf16 Z ----------------
__global__ __launch_bounds__(256) void normalize_kernel(
    const float* __restrict__ x, const float* __restrict__ y,
    __hip_bfloat16* __restrict__ zb) {
  const int r = blockIdx.x;          // 0..8191
  const int t = threadIdx.x;         // 0..255
  const float* src = (r < 4096) ? (x + (size_t)r * DDIM) : (y + (size_t)(r - 4096) * DDIM);
  float v = src[t];
  float ss = v * v;
  #pragma unroll
  for (int off = 32; off > 0; off >>= 1) ss += __shfl_xor(ss, off, 64);
  __shared__ float wsum[4];
  const int w = t >> 6, lane = t & 63;
  if (lane == 0) wsum[w] = ss;
  __syncthreads();
  const float tot = wsum[0] + wsum[1] + wsum[2] + wsum[3];
  const float scale = 1.0f / fmaxf(sqrtf(tot), 1e-8f);
  zb[(size_t)r * DDIM + t] = __float2bfloat16(v * scale);
}

// ---------------- K1b: tsum = sum_i 2*(xn_i . yn_i) ----------------
__global__ __launch_bounds__(256) void diag_kernel(
    const __hip_bfloat16* __restrict__ zb, float* __restrict__ tsum) {
  const int i = blockIdx.x;          // 0..4095
  const int t = threadIdx.x;
  float a = __bfloat162float(zb[(size_t)i * DDIM + t]);
  float b = __bfloat162float(zb[(size_t)(i + 4096) * DDIM + t]);
  float p = a * b;
  #pragma unroll
  for (int off = 32; off > 0; off >>= 1) p += __shfl_xor(p, off, 64);
  __shared__ float wsum[4];
  const int w = t >> 6, lane = t & 63;
  if (lane == 0) wsum[w] = p;
  __syncthreads();
  if (t == 0) {
    atomicAdd(tsum, (wsum[0] + wsum[1] + wsum[2] + wsum[3]) * 2.0f);  // * inv_tau
  }
}

// ---------------- K2: fused Gram + per-row sum of exp ----------------
// Block: 512 threads = 8 waves. Each wave owns 16 rows (full K=256 A-frags in
// registers). Column loop: BN=64 keys staged in LDS (32 KB), XOR-swizzled via
// pre-swizzled global source addresses (linear global_load_lds dest).
__global__ __launch_bounds__(512) void gram_lse_kernel(
    const __hip_bfloat16* __restrict__ zbh, float* __restrict__ rowsum) {
  __shared__ short smem[BN * DDIM];  // 32 KB

  const short* zs = (const short*)zbh;
  const int tid  = threadIdx.x;
  const int w    = tid >> 6;
  const int lane = tid & 63;
  const int lhi  = lane >> 4;   // 0..3
  const int llo  = lane & 15;   // 0..15
  const int i0 = (blockIdx.x >> 3) * BM;            // row-tile base
  const int c0 = (blockIdx.x & 7) * COLS_PER;       // column-range base

  // A fragments: 16 rows per wave, all of K=256. lane -> row llo, k-group lhi.
  const int arow = i0 + w * 16 + llo;
  bf16x8_t afrag[8];
  #pragma unroll
  for (int ks = 0; ks < 8; ++ks) {
    afrag[ks] = *(const bf16x8_t*)(zs + (size_t)arow * DDIM + ks * 32 + lhi * 8);
  }

  float racc[4] = {0.f, 0.f, 0.f, 0.f};

  for (int ct = 0; ct < COLS_PER / BN; ++ct) {
    const int cb = c0 + ct * BN;
    // Stage BN x 256 bf16 (32 KB): 8 waves x 4 x (64 lanes x 16 B).
    // LDS is linear; swizzle applied on the GLOBAL source address:
    //   lds[cr*512 + slot*16 .. +16) = row (cb+cr) bytes [(slot ^ (cr&31))*16 ..)
    #pragma unroll
    for (int it = 0; it < 4; ++it) {
      const int o    = w * 4096 + it * 1024 + lane * 16;  // this lane's lds byte
      const int cr   = o >> 9;
      const int slot = (o >> 4) & 31;
      const size_t src_byte = (size_t)(cb + cr) * 512 + (size_t)((slot ^ (cr & 31)) << 4);
      __builtin_amdgcn_global_load_lds(
          (as1_cvp)((const char*)zs + src_byte),
          (as3_vp)((char*)smem + w * 4096 + it * 1024),
          16, 0, 0);
    }
    asm volatile("s_waitcnt vmcnt(0)" ::: "memory");
    __syncthreads();

    #pragma unroll
    for (int nt = 0; nt < 4; ++nt) {
      const int cr = nt * 16 + llo;      // key (column) this lane feeds as B
      f32x4_t acc = {0.f, 0.f, 0.f, 0.f};
      #pragma unroll
      for (int ks = 0; ks < 8; ++ks) {
        const int kg = ks * 4 + lhi;     // 16B k-slot
        const bf16x8_t bfrag = *(const bf16x8_t*)(
            (const char*)smem + cr * 512 + ((kg ^ (cr & 31)) << 4));
        acc = __builtin_amdgcn_mfma_f32_16x16x32_bf16(afrag[ks], bfrag, acc, 0, 0, 0);
      }
      const int gc = cb + cr;
      #pragma unroll
      for (int j = 0; j < 4; ++j) {
        const int gr = i0 + w * 16 + lhi * 4 + j;   // C/D: row=(lane>>4)*4+j, col=lane&15
        const float s = acc[j] * 2.0f;              // * inv_tau
        racc[j] += (gr != gc) ? __expf(s) : 0.f;    // exclude diagonal
      }
    }
    __syncthreads();
  }

  // Reduce each row's partial sum across the 16 lanes that held its columns.
  #pragma unroll
  for (int j = 0; j < 4; ++j) {
    float v = racc[j];
    v += __shfl_xor(v, 1, 16);
    v += __shfl_xor(v, 2, 16);
    v += __shfl_xor(v, 4, 16);
    v += __shfl_xor(v, 8, 16);
    if (llo == 0) {
      const int gr = i0 + w * 16 + lhi * 4 + j;
      atomicAdd(&rowsum[gr], v);
    }
  }
}

// ---------------- K3: loss = (sum_r log(rowsum_r) - 2*tsum) / 2n ----------------
__global__ __launch_bounds__(256) void finalize_kernel(
    const float* __restrict__ rowsum, const float* __restrict__ tsum,
    float* __restrict__ out) {
  const int t = threadIdx.x;
  float s = 0.f;
  for (int r = t; r < NROWS; r += 256) s += __logf(rowsum[r]);
  #pragma unroll
  for (int off = 32; off > 0; off >>= 1) s += __shfl_xor(s, off, 64);
  __shared__ float wsum[4];
  const int w = t >> 6, lane = t & 63;
  if (lane == 0) wsum[w] = s;
  __syncthreads();
  if (t == 0) {
    const float total = wsum[0] + wsum[1] + wsum[2] + wsum[3];
    out[0] = (total - 2.0f * tsum[0]) / (float)NROWS;
  }
}

extern "C" void kernel_launch(void* const* d_in, const int* in_sizes, int n_in,
                              void* d_out, int out_size, void* d_ws, size_t ws_size,
                              hipStream_t stream) {
  const float* x = (const float*)d_in[0];
  const float* y = (const float*)d_in[1];
  float* out = (float*)d_out;

  char* ws = (char*)d_ws;
  __hip_bfloat16* zb = (__hip_bfloat16*)ws;                       // 4 MB
  float* rowsum = (float*)(ws + (size_t)NROWS * DDIM * 2);        // 32 KB
  float* tsum   = rowsum + NROWS;                                 // 4 B

  normalize_kernel<<<NROWS, 256, 0, stream>>>(x, y, zb);
  hipMemsetAsync(rowsum, 0, (NROWS + 1) * sizeof(float), stream);
  diag_kernel<<<4096, 256, 0, stream>>>(zb, tsum);
  gram_lse_kernel<<<512, 512, 0, stream>>>(zb, rowsum);
  finalize_kernel<<<1, 256, 0, stream>>>(rowsum, tsum, out);
}

// Round 2
// 65.621 us; speedup vs baseline: 1.8150x; 1.8150x over previous
//
#include <hip/hip_runtime.h>
#include <hip/hip_bf16.h>

// InfoNCE loss, N=4096, D=256, tau=0.5.
// loss = (1/2n)[ sum_r log(sum_{k!=r} exp(2*Z_r.Z_k)) - 2*sum_i 2*(xn_i.yn_i) ]
// where Z = concat(xn, yn), rows L2-normalized.
// Scores bounded in [-2,2] -> sum-of-exp needs no running max.

#define NROWS 8192
#define DDIM  256
#define BM    128        // rows per block
#define BN    64         // cols per LDS tile
#define COLSPLIT 8       // column split -> grid = 64 * 8 = 512 blocks
#define COLS_PER (NROWS / COLSPLIT)   // 1024

typedef __attribute__((ext_vector_type(8))) __bf16 bf16x8_t;
typedef __attribute__((ext_vector_type(4))) float  f32x4_t;

typedef __attribute__((address_space(1))) const void* as1_cvp;
typedef __attribute__((address_space(3))) void*       as3_vp;

#if __has_builtin(__builtin_amdgcn_exp2f)
#define EXP2F __builtin_amdgcn_exp2f
#else
#define EXP2F exp2f
#endif

// 2 * log2(e) : folds inv_tau and the exp->exp2 conversion into one constant.
#define TWO_LOG2E 2.8853900817779268f

// ---------------- K1: normalize rows + per-pair diag dot (no atomics) --------
// One wave per row pair (x_i, y_i): float4 loads, fused 3-value shuffle reduce.
__global__ __launch_bounds__(256) void normalize_diag_kernel(
    const float* __restrict__ x, const float* __restrict__ y,
    __hip_bfloat16* __restrict__ zb, float* __restrict__ rowdiag) {
  const int w = threadIdx.x >> 6, lane = threadIdx.x & 63;
  const int i = blockIdx.x * 4 + w;           // 0..4095
  const float4 xv = ((const float4*)(x + (size_t)i * DDIM))[lane];
  const float4 yv = ((const float4*)(y + (size_t)i * DDIM))[lane];
  float ssx = xv.x * xv.x + xv.y * xv.y + xv.z * xv.z + xv.w * xv.w;
  float ssy = yv.x * yv.x + yv.y * yv.y + yv.z * yv.z + yv.w * yv.w;
  float sxy = xv.x * yv.x + xv.y * yv.y + xv.z * yv.z + xv.w * yv.w;
  #pragma unroll
  for (int off = 32; off > 0; off >>= 1) {
    ssx += __shfl_xor(ssx, off, 64);
    ssy += __shfl_xor(ssy, off, 64);
    sxy += __shfl_xor(sxy, off, 64);
  }
  const float sclx = 1.0f / fmaxf(sqrtf(ssx), 1e-8f);
  const float scly = 1.0f / fmaxf(sqrtf(ssy), 1e-8f);
  __hip_bfloat16 px[4], py[4];
  px[0] = __float2bfloat16(xv.x * sclx); px[1] = __float2bfloat16(xv.y * sclx);
  px[2] = __float2bfloat16(xv.z * sclx); px[3] = __float2bfloat16(xv.w * sclx);
  py[0] = __float2bfloat16(yv.x * scly); py[1] = __float2bfloat16(yv.y * scly);
  py[2] = __float2bfloat16(yv.z * scly); py[3] = __float2bfloat16(yv.w * scly);
  *(short4*)(zb + (size_t)i * DDIM + lane * 4)            = *(short4*)px;
  *(short4*)(zb + (size_t)(i + 4096) * DDIM + lane * 4)   = *(short4*)py;
  if (lane == 0) rowdiag[i] = 2.0f * sxy * sclx * scly;   // = s_ii (inv_tau folded)
}

// ---------------- K2: fused Gram + per-row sum of exp ----------------
// Block: 512 threads = 8 waves. Each wave owns 16 rows (full K=256 A-frags in
// registers). Column loop: BN=64 keys staged in LDS (32 KB), XOR-swizzled via
// pre-swizzled global source addresses (linear global_load_lds dest).
__global__ __launch_bounds__(512) void gram_lse_kernel(
    const __hip_bfloat16* __restrict__ zbh, float* __restrict__ rowsum) {
  __shared__ short smem[BN * DDIM];  // 32 KB

  const short* zs = (const short*)zbh;
  const int tid  = threadIdx.x;
  const int w    = tid >> 6;
  const int lane = tid & 63;
  const int lhi  = lane >> 4;   // 0..3
  const int llo  = lane & 15;   // 0..15
  const int i0 = (blockIdx.x >> 3) * BM;            // row-tile base
  const int c0 = (blockIdx.x & 7) * COLS_PER;       // column-range base

  // A fragments: 16 rows per wave, all of K=256. lane -> row llo, k-group lhi.
  const int arow = i0 + w * 16 + llo;
  bf16x8_t afrag[8];
  #pragma unroll
  for (int ks = 0; ks < 8; ++ks) {
    afrag[ks] = *(const bf16x8_t*)(zs + (size_t)arow * DDIM + ks * 32 + lhi * 8);
  }

  float racc[4] = {0.f, 0.f, 0.f, 0.f};

  for (int ct = 0; ct < COLS_PER / BN; ++ct) {
    const int cb = c0 + ct * BN;
    // Stage BN x 256 bf16 (32 KB): 8 waves x 4 x (64 lanes x 16 B).
    // LDS is linear; swizzle applied on the GLOBAL source address:
    //   lds[cr*512 + slot*16 .. +16) = row (cb+cr) bytes [(slot ^ (cr&31))*16 ..)
    #pragma unroll
    for (int it = 0; it < 4; ++it) {
      const int o    = w * 4096 + it * 1024 + lane * 16;  // this lane's lds byte
      const int cr   = o >> 9;
      const int slot = (o >> 4) & 31;
      const size_t src_byte = (size_t)(cb + cr) * 512 + (size_t)((slot ^ (cr & 31)) << 4);
      __builtin_amdgcn_global_load_lds(
          (as1_cvp)((const char*)zs + src_byte),
          (as3_vp)((char*)smem + w * 4096 + it * 1024),
          16, 0, 0);
    }
    asm volatile("s_waitcnt vmcnt(0)" ::: "memory");
    __syncthreads();

    #pragma unroll
    for (int nt = 0; nt < 4; ++nt) {
      const int cr = nt * 16 + llo;      // key (column) this lane feeds as B
      f32x4_t acc = {0.f, 0.f, 0.f, 0.f};
      #pragma unroll
      for (int ks = 0; ks < 8; ++ks) {
        const int kg = ks * 4 + lhi;     // 16B k-slot
        const bf16x8_t bfrag = *(const bf16x8_t*)(
            (const char*)smem + cr * 512 + ((kg ^ (cr & 31)) << 4));
        acc = __builtin_amdgcn_mfma_f32_16x16x32_bf16(afrag[ks], bfrag, acc, 0, 0, 0);
      }
      const int gc = cb + cr;
      #pragma unroll
      for (int j = 0; j < 4; ++j) {
        const int gr = i0 + w * 16 + lhi * 4 + j;   // C/D: row=(lane>>4)*4+j, col=lane&15
        racc[j] += (gr != gc) ? EXP2F(acc[j] * TWO_LOG2E) : 0.f;  // exclude diagonal
      }
    }
    __syncthreads();
  }

  // Reduce each row's partial sum across the 16 lanes that held its columns.
  #pragma unroll
  for (int j = 0; j < 4; ++j) {
    float v = racc[j];
    v += __shfl_xor(v, 1, 16);
    v += __shfl_xor(v, 2, 16);
    v += __shfl_xor(v, 4, 16);
    v += __shfl_xor(v, 8, 16);
    if (llo == 0) {
      const int gr = i0 + w * 16 + lhi * 4 + j;
      atomicAdd(&rowsum[gr], v);   // 8 adds per row address -> negligible contention
    }
  }
}

// ------- K3: loss = (sum_r log(rowsum_r) - 2*sum_i rowdiag_i) / 2n -------
__global__ __launch_bounds__(256) void finalize_kernel(
    const float* __restrict__ rowsum, const float* __restrict__ rowdiag,
    float* __restrict__ out) {
  const int t = threadIdx.x;
  float s = 0.f;
  for (int r = t; r < NROWS; r += 256) s += __logf(rowsum[r]);
  for (int i = t; i < 4096; i += 256) s -= 2.0f * rowdiag[i];
  #pragma unroll
  for (int off = 32; off > 0; off >>= 1) s += __shfl_xor(s, off, 64);
  __shared__ float wsum[4];
  const int w = t >> 6, lane = t & 63;
  if (lane == 0) wsum[w] = s;
  __syncthreads();
  if (t == 0) out[0] = (wsum[0] + wsum[1] + wsum[2] + wsum[3]) / (float)NROWS;
}

extern "C" void kernel_launch(void* const* d_in, const int* in_sizes, int n_in,
                              void* d_out, int out_size, void* d_ws, size_t ws_size,
                              hipStream_t stream) {
  const float* x = (const float*)d_in[0];
  const float* y = (const float*)d_in[1];
  float* out = (float*)d_out;

  char* ws = (char*)d_ws;
  __hip_bfloat16* zb = (__hip_bfloat16*)ws;                       // 4 MB
  float* rowsum  = (float*)(ws + (size_t)NROWS * DDIM * 2);       // 32 KB
  float* rowdiag = rowsum + NROWS;                                // 16 KB

  normalize_diag_kernel<<<1024, 256, 0, stream>>>(x, y, zb, rowdiag);
  hipMemsetAsync(rowsum, 0, NROWS * sizeof(float), stream);
  gram_lse_kernel<<<512, 512, 0, stream>>>(zb, rowsum);
  finalize_kernel<<<1, 256, 0, stream>>>(rowsum, rowdiag, out);
}

// Round 3
// 55.348 us; speedup vs baseline: 2.1519x; 1.1856x over previous
//
#include <hip/hip_runtime.h>
#include <hip/hip_bf16.h>

// InfoNCE loss, N=4096, D=256, tau=0.5.
// loss = (1/2n)[ sum_r log(sum_{k!=r} exp(2*Z_r.Z_k)) - 2*sum_i 2*(xn_i.yn_i) ]
// where Z = concat(xn, yn), rows L2-normalized. Scores bounded in [-2,2]
// -> sum-of-exp needs no running max.
// The 2/tau * log2(e) factor is folded into the A-side MFMA fragments
// (bf16 rescale in registers), so the epilogue is pure exp2 + add.

#define NROWS 8192
#define DDIM  256
#define BM    128        // rows per block
#define BN    64         // cols per LDS tile
#define COLSPLIT 8       // column split -> grid = 64 * 8 = 512 blocks
#define COLS_PER (NROWS / COLSPLIT)   // 1024
#define NT (COLS_PER / BN)            // 16 tiles

typedef __attribute__((ext_vector_type(8))) __bf16 bf16x8_t;
typedef __attribute__((ext_vector_type(4))) float  f32x4_t;

typedef __attribute__((address_space(1))) const void* as1_cvp;
typedef __attribute__((address_space(3))) void*       as3_vp;

#if __has_builtin(__builtin_amdgcn_exp2f)
#define EXP2F __builtin_amdgcn_exp2f
#else
#define EXP2F exp2f
#endif

#define TWO_LOG2E 2.8853900817779268f

// ---------------- K1: normalize rows + per-pair diag dot + rowsum zeroing ----
// One wave per row pair (x_i, y_i): float4 loads, fused 3-value shuffle reduce.
__global__ __launch_bounds__(256) void normalize_diag_kernel(
    const float* __restrict__ x, const float* __restrict__ y,
    __hip_bfloat16* __restrict__ zb, float* __restrict__ rowdiag,
    float* __restrict__ rowsum) {
  // fused rowsum zeroing (replaces hipMemsetAsync dispatch)
  const int g = blockIdx.x * 256 + threadIdx.x;
  if (g < NROWS) rowsum[g] = 0.f;

  const int w = threadIdx.x >> 6, lane = threadIdx.x & 63;
  const int i = blockIdx.x * 4 + w;           // 0..4095
  const float4 xv = ((const float4*)(x + (size_t)i * DDIM))[lane];
  const float4 yv = ((const float4*)(y + (size_t)i * DDIM))[lane];
  float ssx = xv.x * xv.x + xv.y * xv.y + xv.z * xv.z + xv.w * xv.w;
  float ssy = yv.x * yv.x + yv.y * yv.y + yv.z * yv.z + yv.w * yv.w;
  float sxy = xv.x * yv.x + xv.y * yv.y + xv.z * yv.z + xv.w * yv.w;
  #pragma unroll
  for (int off = 32; off > 0; off >>= 1) {
    ssx += __shfl_xor(ssx, off, 64);
    ssy += __shfl_xor(ssy, off, 64);
    sxy += __shfl_xor(sxy, off, 64);
  }
  const float sclx = 1.0f / fmaxf(sqrtf(ssx), 1e-8f);
  const float scly = 1.0f / fmaxf(sqrtf(ssy), 1e-8f);
  __hip_bfloat16 px[4], py[4];
  px[0] = __float2bfloat16(xv.x * sclx); px[1] = __float2bfloat16(xv.y * sclx);
  px[2] = __float2bfloat16(xv.z * sclx); px[3] = __float2bfloat16(xv.w * sclx);
  py[0] = __float2bfloat16(yv.x * scly); py[1] = __float2bfloat16(yv.y * scly);
  py[2] = __float2bfloat16(yv.z * scly); py[3] = __float2bfloat16(yv.w * scly);
  *(short4*)(zb + (size_t)i * DDIM + lane * 4)            = *(short4*)px;
  *(short4*)(zb + (size_t)(i + 4096) * DDIM + lane * 4)   = *(short4*)py;
  if (lane == 0) rowdiag[i] = 2.0f * sxy * sclx * scly;   // target score (f32)
}

// ---------------- K2: fused Gram + per-row sum of exp ----------------
// 512 threads = 8 waves; each wave owns 16 rows (full K=256 A-frags in regs,
// pre-scaled by bf16(2*log2e)). Column loop: BN=64 keys double-buffered in
// LDS (2 x 32 KB), prefetched via global_load_lds with XOR-swizzled global
// source addresses (linear LDS dest); single vmcnt(0)+barrier per tile.
__global__ __launch_bounds__(512) void gram_lse_kernel(
    const __hip_bfloat16* __restrict__ zbh, float* __restrict__ rowsum) {
  __shared__ short smem[2][BN * DDIM];  // 64 KB

  const short* zs = (const short*)zbh;
  const char* zbytes = (const char*)zs;
  const int tid  = threadIdx.x;
  const int w    = tid >> 6;
  const int lane = tid & 63;
  const int lhi  = lane >> 4;   // 0..3
  const int llo  = lane & 15;   // 0..15
  const int i0 = (blockIdx.x >> 3) * BM;            // row-tile base
  const int c0 = (blockIdx.x & 7) * COLS_PER;       // column-range base
  // Rows [i0,i0+128) have their diagonal inside [c0,c0+1024) iff:
  const bool has_diag = ((blockIdx.x >> 6) == (blockIdx.x & 7));

  // A fragments: 16 rows per wave, all of K=256. lane -> row llo, k-group lhi.
  // Pre-scale by bf16(2*log2e): MFMA then yields score*log2(e) directly.
  const int arow = i0 + w * 16 + llo;
  const float TBF = __bfloat162float(__float2bfloat16(TWO_LOG2E));
  bf16x8_t afrag[8];
  #pragma unroll
  for (int ks = 0; ks < 8; ++ks) {
    afrag[ks] = *(const bf16x8_t*)(zs + (size_t)arow * DDIM + ks * 32 + lhi * 8);
    #pragma unroll
    for (int e = 0; e < 8; ++e) {
      afrag[ks][e] = (__bf16)((float)afrag[ks][e] * TBF);
    }
  }

  // Hoisted per-lane staging offsets. Stage layout per tile:
  //   lds[cr*512 + slot*16 .. +16) = row (cb+cr) bytes [(slot ^ (cr&31))*16 ..)
  size_t soff[4]; int loff[4];
  #pragma unroll
  for (int it = 0; it < 4; ++it) {
    const int o    = w * 4096 + it * 1024 + lane * 16;
    const int cr   = o >> 9;
    const int slot = (o >> 4) & 31;
    soff[it] = (size_t)cr * 512 + (size_t)((slot ^ (cr & 31)) << 4);
    loff[it] = w * 4096 + it * 1024;
  }

#define STAGE(buf, ct_) do {                                                  \
    const size_t cbase = (size_t)(c0 + (ct_) * BN) * 512;                     \
    _Pragma("unroll")                                                         \
    for (int it = 0; it < 4; ++it) {                                          \
      __builtin_amdgcn_global_load_lds(                                       \
          (as1_cvp)(zbytes + cbase + soff[it]),                               \
          (as3_vp)((char*)smem[buf] + loff[it]), 16, 0, 0);                   \
    }                                                                         \
  } while (0)

  float racc[4] = {0.f, 0.f, 0.f, 0.f};
  const int gr_base = i0 + w * 16 + lhi * 4;   // C/D row = (lane>>4)*4 + j

  STAGE(0, 0);
  asm volatile("s_waitcnt vmcnt(0)" ::: "memory");
  __syncthreads();
  int cur = 0;

  for (int ct = 0; ct < NT; ++ct) {
    if (ct + 1 < NT) STAGE(cur ^ 1, ct + 1);   // prefetch overlaps compute
    const int cb = c0 + ct * BN;

    #pragma unroll
    for (int nt = 0; nt < 4; ++nt) {
      const int cr = nt * 16 + llo;      // key (column) this lane feeds as B
      f32x4_t acc = {0.f, 0.f, 0.f, 0.f};
      #pragma unroll
      for (int ks = 0; ks < 8; ++ks) {
        const int kg = ks * 4 + lhi;     // 16B k-slot
        const bf16x8_t bfrag = *(const bf16x8_t*)(
            (const char*)smem[cur] + cr * 512 + ((kg ^ (cr & 31)) << 4));
        acc = __builtin_amdgcn_mfma_f32_16x16x32_bf16(afrag[ks], bfrag, acc, 0, 0, 0);
      }
      if (has_diag) {                    // block-uniform branch (64/512 blocks)
        const int gc = cb + cr;
        #pragma unroll
        for (int j = 0; j < 4; ++j)
          racc[j] += ((gr_base + j) != gc) ? EXP2F(acc[j]) : 0.f;
      } else {
        #pragma unroll
        for (int j = 0; j < 4; ++j)
          racc[j] += EXP2F(acc[j]);
      }
    }
    asm volatile("s_waitcnt vmcnt(0)" ::: "memory");  // prefetched tile landed
    __syncthreads();
    cur ^= 1;
  }
#undef STAGE

  // Reduce each row's partial sum across the 16 lanes that held its columns.
  #pragma unroll
  for (int j = 0; j < 4; ++j) {
    float v = racc[j];
    v += __shfl_xor(v, 1, 16);
    v += __shfl_xor(v, 2, 16);
    v += __shfl_xor(v, 4, 16);
    v += __shfl_xor(v, 8, 16);
    if (llo == 0) atomicAdd(&rowsum[gr_base + j], v);  // 8 adds/row address
  }
}

// ------- K3: loss = (sum_r log(rowsum_r) - 2*sum_i rowdiag_i) / 2n -------
__global__ __launch_bounds__(256) void finalize_kernel(
    const float* __restrict__ rowsum, const float* __restrict__ rowdiag,
    float* __restrict__ out) {
  const int t = threadIdx.x;
  float s = 0.f;
  for (int r4 = t; r4 < NROWS / 4; r4 += 256) {
    const float4 v = ((const float4*)rowsum)[r4];
    s += __logf(v.x) + __logf(v.y) + __logf(v.z) + __logf(v.w);
  }
  for (int i4 = t; i4 < 4096 / 4; i4 += 256) {
    const float4 d = ((const float4*)rowdiag)[i4];
    s -= 2.0f * (d.x + d.y + d.z + d.w);
  }
  #pragma unroll
  for (int off = 32; off > 0; off >>= 1) s += __shfl_xor(s, off, 64);
  __shared__ float wsum[4];
  const int w = t >> 6, lane = t & 63;
  if (lane == 0) wsum[w] = s;
  __syncthreads();
  if (t == 0) out[0] = (wsum[0] + wsum[1] + wsum[2] + wsum[3]) / (float)NROWS;
}

extern "C" void kernel_launch(void* const* d_in, const int* in_sizes, int n_in,
                              void* d_out, int out_size, void* d_ws, size_t ws_size,
                              hipStream_t stream) {
  const float* x = (const float*)d_in[0];
  const float* y = (const float*)d_in[1];
  float* out = (float*)d_out;

  char* ws = (char*)d_ws;
  __hip_bfloat16* zb = (__hip_bfloat16*)ws;                       // 4 MB
  float* rowsum  = (float*)(ws + (size_t)NROWS * DDIM * 2);       // 32 KB
  float* rowdiag = rowsum + NROWS;                                // 16 KB

  normalize_diag_kernel<<<1024, 256, 0, stream>>>(x, y, zb, rowdiag, rowsum);
  gram_lse_kernel<<<512, 512, 0, stream>>>(zb, rowsum);
  finalize_kernel<<<1, 256, 0, stream>>>(rowsum, rowdiag, out);
}

// Round 4
// 55.163 us; speedup vs baseline: 2.1591x; 1.0033x over previous
//
#include <hip/hip_runtime.h>
#include <hip/hip_bf16.h>

// InfoNCE loss, N=4096, D=256, tau=0.5.
// loss = (1/2n)[ sum_r log(sum_{k!=r} exp(2*Z_r.Z_k)) - 2*sum_i 2*(xn_i.yn_i) ]
// where Z = concat(xn, yn), rows L2-normalized. Scores bounded in [-2,2]
// -> sum-of-exp needs no running max.
// 2/tau * log2(e) folded into the A-side fragments; epilogue = pure exp2+add.
// R4: each wave owns 32 rows (2 A-frag sets) so every LDS B-fragment read
// feeds 2 MFMAs -> LDS traffic halves (was the measured bottleneck: 50 TB/s
// ~ 72% of LDS ceiling at R3).

#define NROWS 8192
#define DDIM  256
#define BM    128        // rows per block = 4 waves * 32 rows
#define BN    64         // cols per LDS tile
#define COLSPLIT 8       // column split -> grid = 64 * 8 = 512 blocks
#define COLS_PER (NROWS / COLSPLIT)   // 1024
#define NT (COLS_PER / BN)            // 16 tiles

typedef __attribute__((ext_vector_type(8))) __bf16 bf16x8_t;
typedef __attribute__((ext_vector_type(4))) float  f32x4_t;

typedef __attribute__((address_space(1))) const void* as1_cvp;
typedef __attribute__((address_space(3))) void*       as3_vp;

#if __has_builtin(__builtin_amdgcn_exp2f)
#define EXP2F __builtin_amdgcn_exp2f
#else
#define EXP2F exp2f
#endif

#define TWO_LOG2E 2.8853900817779268f

// ---------------- K1: normalize rows + per-pair diag dot + rowsum zeroing ----
__global__ __launch_bounds__(256) void normalize_diag_kernel(
    const float* __restrict__ x, const float* __restrict__ y,
    __hip_bfloat16* __restrict__ zb, float* __restrict__ rowdiag,
    float* __restrict__ rowsum) {
  const int g = blockIdx.x * 256 + threadIdx.x;
  if (g < NROWS) rowsum[g] = 0.f;

  const int w = threadIdx.x >> 6, lane = threadIdx.x & 63;
  const int i = blockIdx.x * 4 + w;           // 0..4095
  const float4 xv = ((const float4*)(x + (size_t)i * DDIM))[lane];
  const float4 yv = ((const float4*)(y + (size_t)i * DDIM))[lane];
  float ssx = xv.x * xv.x + xv.y * xv.y + xv.z * xv.z + xv.w * xv.w;
  float ssy = yv.x * yv.x + yv.y * yv.y + yv.z * yv.z + yv.w * yv.w;
  float sxy = xv.x * yv.x + xv.y * yv.y + xv.z * yv.z + xv.w * yv.w;
  #pragma unroll
  for (int off = 32; off > 0; off >>= 1) {
    ssx += __shfl_xor(ssx, off, 64);
    ssy += __shfl_xor(ssy, off, 64);
    sxy += __shfl_xor(sxy, off, 64);
  }
  const float sclx = 1.0f / fmaxf(sqrtf(ssx), 1e-8f);
  const float scly = 1.0f / fmaxf(sqrtf(ssy), 1e-8f);
  __hip_bfloat16 px[4], py[4];
  px[0] = __float2bfloat16(xv.x * sclx); px[1] = __float2bfloat16(xv.y * sclx);
  px[2] = __float2bfloat16(xv.z * sclx); px[3] = __float2bfloat16(xv.w * sclx);
  py[0] = __float2bfloat16(yv.x * scly); py[1] = __float2bfloat16(yv.y * scly);
  py[2] = __float2bfloat16(yv.z * scly); py[3] = __float2bfloat16(yv.w * scly);
  *(short4*)(zb + (size_t)i * DDIM + lane * 4)            = *(short4*)px;
  *(short4*)(zb + (size_t)(i + 4096) * DDIM + lane * 4)   = *(short4*)py;
  if (lane == 0) rowdiag[i] = 2.0f * sxy * sclx * scly;   // target score (f32)
}

// ---------------- K2: fused Gram + per-row sum of exp ----------------
// 256 threads = 4 waves; each wave owns 32 rows (2 A-frag sets, pre-scaled by
// bf16(2*log2e)) x 64 cols per tile. BN=64 keys double-buffered in LDS
// (2 x 32 KB), prefetched via global_load_lds with XOR-swizzled global source
// addresses (linear LDS dest); one vmcnt(0)+barrier per tile. Every B-frag
// ds_read_b128 feeds 2 MFMAs -> 512 B LDS/MFMA.
__global__ __launch_bounds__(256) void gram_lse_kernel(
    const __hip_bfloat16* __restrict__ zbh, float* __restrict__ rowsum) {
  __shared__ short smem[2][BN * DDIM];  // 64 KB

  const short* zs = (const short*)zbh;
  const char* zbytes = (const char*)zs;
  const int tid  = threadIdx.x;
  const int w    = tid >> 6;    // 0..3
  const int lane = tid & 63;
  const int lhi  = lane >> 4;   // 0..3
  const int llo  = lane & 15;   // 0..15
  const int i0 = (blockIdx.x >> 3) * BM;            // row-tile base
  const int c0 = (blockIdx.x & 7) * COLS_PER;       // column-range base
  const bool has_diag = ((blockIdx.x >> 6) == (blockIdx.x & 7));

  // Two A-fragment sets: rows arow0 (set a) and arow0+16 (set b), full K=256.
  // Pre-scale by bf16(2*log2e): MFMA then yields score*log2(e) directly.
  const int arow0 = i0 + w * 32 + llo;
  const float TBF = __bfloat162float(__float2bfloat16(TWO_LOG2E));
  bf16x8_t afa[8], afb[8];
  #pragma unroll
  for (int ks = 0; ks < 8; ++ks) {
    afa[ks] = *(const bf16x8_t*)(zs + (size_t)arow0 * DDIM + ks * 32 + lhi * 8);
    afb[ks] = *(const bf16x8_t*)(zs + (size_t)(arow0 + 16) * DDIM + ks * 32 + lhi * 8);
    #pragma unroll
    for (int e = 0; e < 8; ++e) {
      afa[ks][e] = (__bf16)((float)afa[ks][e] * TBF);
      afb[ks][e] = (__bf16)((float)afb[ks][e] * TBF);
    }
  }

  // Hoisted staging offsets. Tile layout (linear LDS dest, swizzled source):
  //   lds[cr*512 + slot*16 .. +16) = row (cb+cr) bytes [(slot ^ (cr&31))*16 ..)
  // 256 threads x 16 B = 4 KB per it, 8 its = 32 KB tile.
  int soff[8], loff[8];
  #pragma unroll
  for (int it = 0; it < 8; ++it) {
    const int o    = it * 4096 + tid * 16;
    const int cr   = o >> 9;
    const int slot = (o >> 4) & 31;
    soff[it] = cr * 512 + ((slot ^ (cr & 31)) << 4);
    loff[it] = it * 4096 + w * 1024;   // wave-uniform dest base
  }

#define STAGE(buf, ct_) do {                                                  \
    const size_t cbase = (size_t)(c0 + (ct_) * BN) * 512;                     \
    _Pragma("unroll")                                                         \
    for (int it = 0; it < 8; ++it) {                                          \
      __builtin_amdgcn_global_load_lds(                                       \
          (as1_cvp)(zbytes + cbase + (size_t)soff[it]),                       \
          (as3_vp)((char*)smem[buf] + loff[it]), 16, 0, 0);                   \
    }                                                                         \
  } while (0)

  float racc0[4] = {0.f, 0.f, 0.f, 0.f};
  float racc1[4] = {0.f, 0.f, 0.f, 0.f};
  const int gr0 = i0 + w * 32 + lhi * 4;   // C/D row = (lane>>4)*4 + j
  const int gr1 = gr0 + 16;

  STAGE(0, 0);
  asm volatile("s_waitcnt vmcnt(0)" ::: "memory");
  __syncthreads();
  int cur = 0;

  for (int ct = 0; ct < NT; ++ct) {
    if (ct + 1 < NT) STAGE(cur ^ 1, ct + 1);   // prefetch overlaps compute
    const int cb = c0 + ct * BN;

    #pragma unroll
    for (int nt = 0; nt < 4; ++nt) {
      const int cr = nt * 16 + llo;      // key (column) this lane feeds as B
      f32x4_t acc0 = {0.f, 0.f, 0.f, 0.f};
      f32x4_t acc1 = {0.f, 0.f, 0.f, 0.f};
      #pragma unroll
      for (int ks = 0; ks < 8; ++ks) {
        const int kg = ks * 4 + lhi;     // 16B k-slot
        const bf16x8_t bfrag = *(const bf16x8_t*)(
            (const char*)smem[cur] + cr * 512 + ((kg ^ (cr & 31)) << 4));
        acc0 = __builtin_amdgcn_mfma_f32_16x16x32_bf16(afa[ks], bfrag, acc0, 0, 0, 0);
        acc1 = __builtin_amdgcn_mfma_f32_16x16x32_bf16(afb[ks], bfrag, acc1, 0, 0, 0);
      }
      if (has_diag) {                    // block-uniform branch (64/512 blocks)
        const int gc = cb + cr;
        #pragma unroll
        for (int j = 0; j < 4; ++j) {
          racc0[j] += ((gr0 + j) != gc) ? EXP2F(acc0[j]) : 0.f;
          racc1[j] += ((gr1 + j) != gc) ? EXP2F(acc1[j]) : 0.f;
        }
      } else {
        #pragma unroll
        for (int j = 0; j < 4; ++j) {
          racc0[j] += EXP2F(acc0[j]);
          racc1[j] += EXP2F(acc1[j]);
        }
      }
    }
    asm volatile("s_waitcnt vmcnt(0)" ::: "memory");  // prefetched tile landed
    __syncthreads();
    cur ^= 1;
  }
#undef STAGE

  // Reduce each row's partial sum across the 16 lanes that held its columns.
  #pragma unroll
  for (int j = 0; j < 4; ++j) {
    float v0 = racc0[j], v1 = racc1[j];
    v0 += __shfl_xor(v0, 1, 16); v1 += __shfl_xor(v1, 1, 16);
    v0 += __shfl_xor(v0, 2, 16); v1 += __shfl_xor(v1, 2, 16);
    v0 += __shfl_xor(v0, 4, 16); v1 += __shfl_xor(v1, 4, 16);
    v0 += __shfl_xor(v0, 8, 16); v1 += __shfl_xor(v1, 8, 16);
    if (llo == 0) {
      atomicAdd(&rowsum[gr0 + j], v0);   // 8 adds/row address
      atomicAdd(&rowsum[gr1 + j], v1);
    }
  }
}

// ------- K3: loss = (sum_r log(rowsum_r) - 2*sum_i rowdiag_i) / 2n -------
__global__ __launch_bounds__(256) void finalize_kernel(
    const float* __restrict__ rowsum, const float* __restrict__ rowdiag,
    float* __restrict__ out) {
  const int t = threadIdx.x;
  float s = 0.f;
  for (int r4 = t; r4 < NROWS / 4; r4 += 256) {
    const float4 v = ((const float4*)rowsum)[r4];
    s += __logf(v.x) + __logf(v.y) + __logf(v.z) + __logf(v.w);
  }
  for (int i4 = t; i4 < 4096 / 4; i4 += 256) {
    const float4 d = ((const float4*)rowdiag)[i4];
    s -= 2.0f * (d.x + d.y + d.z + d.w);
  }
  #pragma unroll
  for (int off = 32; off > 0; off >>= 1) s += __shfl_xor(s, off, 64);
  __shared__ float wsum[4];
  const int w = t >> 6, lane = t & 63;
  if (lane == 0) wsum[w] = s;
  __syncthreads();
  if (t == 0) out[0] = (wsum[0] + wsum[1] + wsum[2] + wsum[3]) / (float)NROWS;
}

extern "C" void kernel_launch(void* const* d_in, const int* in_sizes, int n_in,
                              void* d_out, int out_size, void* d_ws, size_t ws_size,
                              hipStream_t stream) {
  const float* x = (const float*)d_in[0];
  const float* y = (const float*)d_in[1];
  float* out = (float*)d_out;

  char* ws = (char*)d_ws;
  __hip_bfloat16* zb = (__hip_bfloat16*)ws;                       // 4 MB
  float* rowsum  = (float*)(ws + (size_t)NROWS * DDIM * 2);       // 32 KB
  float* rowdiag = rowsum + NROWS;                                // 16 KB

  normalize_diag_kernel<<<1024, 256, 0, stream>>>(x, y, zb, rowdiag, rowsum);
  gram_lse_kernel<<<512, 256, 0, stream>>>(zb, rowsum);
  finalize_kernel<<<1, 256, 0, stream>>>(rowsum, rowdiag, out);
}